// Round 10
// baseline (156.158 us; speedup 1.0000x reference)
//
#include <hip/hip_runtime.h>

// GINConv: out = (1+eps)*feat + segment_sum(feat[edge_src], edge_dst)
// N=100000, D=64 fp32, E=1200000.
//
// Round 21 = Round 20 resubmitted verbatim (R20 bench was an infra failure:
// "MI355X container failed twice" -- no measurement taken).
//
// Round 20: budget model says dur_us = K1(~31) + gather(~41) + fixed
// (~44us harness fill + gaps). K1 is at a proven plateau (R15/R18/R19).
// Attack gather's latency chain: switch the per-edge feature read from
// 16 lanes x 8B to 8 lanes x 16B (uint4):
//   - r = lane>>3 gives 8 j-slots/trip (was 4): serialized shfl->load
//     trips per quad drop ~5 -> ~3; per 16 nodes 20 -> ~10.
//   - load transactions halve (19.2M -> 9.6M), same bytes.
//   - 8 fp32 accumulators/node, 3-stage butterfly (xor 8/16/32),
//     lanes 0..7 write 2xfloat4 per node (256B coalesced).
// K1 unchanged from R19 (register-carried edges, PB=128).
// Pipeline: memset(bcnt 100KB) -> K1(cast||hist+reserve+place) -> gather.

#define N_NODES 100000
#define D_FEAT  64
#define N_EDGES 1200000

#define BSHIFT  6
#define NPB     64                               // dst nodes per bucket
#define KB      ((N_NODES + NPB - 1) / NPB)      // 1563 (last bucket: 32 nodes)
#define CAP_B   1024                             // mean 768, sigma 27.7 -> +9 sigma
#define NCAP    32                               // per-node list cap
#define OVL_CAP 128                              // per-block overflow list cap
#define CNT_STRIDE 16                            // 64B pad: 1 counter per cacheline

#define PB       128                             // place blocks (1024 thr each)
#define PTH      1024
#define EPB      ((N_EDGES + PB - 1) / PB)       // 9375
#define BN       10                              // edges/thread (10*1024=10240>=9375)
#define CAST_ITEMS (N_NODES * D_FEAT / 8)        // 800000
#define CAST_BLOCKS ((CAST_ITEMS + PTH - 1) / PTH)  // 782

__device__ __forceinline__ unsigned short f32_to_bf16_rne(float f) {
    unsigned int u = __float_as_uint(f);
    u += 0x7fffu + ((u >> 16) & 1u);
    return (unsigned short)(u >> 16);
}
__device__ __forceinline__ float bf_lo(unsigned int q) { return __uint_as_float(q << 16); }
__device__ __forceinline__ float bf_hi(unsigned int q) { return __uint_as_float(q & 0xffff0000u); }

// K1: blocks [0,PB): LDS-hist + reserve + place, edges carried in registers.
//     blocks [PB,..): cast feat -> bf16 pairs.
__global__ __launch_bounds__(1024) void gin_cast_place_kernel(
    const float* __restrict__ feat,
    const int* __restrict__ edge_src,
    const int* __restrict__ edge_dst,
    unsigned int* __restrict__ fb,
    int* __restrict__ bcnt,          // [KB*CNT_STRIDE], pre-zeroed
    int* __restrict__ buckets)       // [KB*CAP_B]
{
    const int tid = threadIdx.x;
    if (blockIdx.x < PB) {
        __shared__ int hist[KB];                 // 6.3 KB
        __shared__ int base[KB];                 // 6.3 KB
        __shared__ int lcur[KB];                 // 6.3 KB
        for (int k = tid; k < KB; k += PTH) { hist[k] = 0; lcur[k] = 0; }
        __syncthreads();

        const int e0 = blockIdx.x * EPB;
        const int e1 = min(e0 + EPB, N_EDGES);

        // single edge read: all BN edges into registers, carried across barriers
        int d[BN], s[BN]; bool v[BN];
        #pragma unroll
        for (int u = 0; u < BN; ++u) {
            const int ee = e0 + tid + u * PTH;
            v[u] = (ee < e1);
            if (v[u]) { d[u] = edge_dst[ee]; s[u] = edge_src[ee]; }
        }
        // pass 1: LDS histogram from registers
        #pragma unroll
        for (int u = 0; u < BN; ++u)
            if (v[u]) atomicAdd(&hist[d[u] >> BSHIFT], 1);   // LDS atomic
        __syncthreads();

        // reserve: one global atomic per (block,bucket)
        for (int k = tid; k < KB; k += PTH) {
            const int h = hist[k];
            if (h > 0) base[k] = atomicAdd(&bcnt[k * CNT_STRIDE], h);
        }
        __syncthreads();

        // pass 2: LDS slot atomic + run-contiguous store (no global reads)
        int t[BN];
        #pragma unroll
        for (int u = 0; u < BN; ++u)
            if (v[u]) t[u] = base[d[u] >> BSHIFT] + atomicAdd(&lcur[d[u] >> BSHIFT], 1);
        #pragma unroll
        for (int u = 0; u < BN; ++u) {
            if (v[u]) {
                const int k = d[u] >> BSHIFT;
                if (t[u] < CAP_B)                // +9 sigma guard (never fires)
                    buckets[k * CAP_B + t[u]] = s[u] | ((d[u] & (NPB - 1)) << 17);
            }
        }
    } else {
        const int i = (blockIdx.x - PB) * PTH + tid;
        if (i < CAST_ITEMS) {
            const float4 f0 = reinterpret_cast<const float4*>(feat)[2 * i];
            const float4 f1 = reinterpret_cast<const float4*>(feat)[2 * i + 1];
            uint4 q;
            q.x = (unsigned)f32_to_bf16_rne(f0.x) | ((unsigned)f32_to_bf16_rne(f0.y) << 16);
            q.y = (unsigned)f32_to_bf16_rne(f0.z) | ((unsigned)f32_to_bf16_rne(f0.w) << 16);
            q.z = (unsigned)f32_to_bf16_rne(f1.x) | ((unsigned)f32_to_bf16_rne(f1.y) << 16);
            q.w = (unsigned)f32_to_bf16_rne(f1.z) | ((unsigned)f32_to_bf16_rne(f1.w) << 16);
            reinterpret_cast<uint4*>(fb)[i] = q;
        }
    }
}

// K2: one block per 64-node bucket. Regroup to per-node LDS lists (NCAP=32),
// then node-QUAD processing with 8-lane feature groups: c=lane&7 owns a 16B
// chunk of the 128B bf16 row, r=lane>>3 gives 8 j-slots per trip. 4 nodes x
// 8 fp32 accumulators, 4 independent shfl->uint4-load chains per trip,
// 3-stage butterfly (xor 8/16/32), fused (1+eps)*feat, 2 float4 stores per
// lane (r==0) per node. Per-node overflow resolved fp32-exact in-block.
__global__ __launch_bounds__(256) void gin_gather_kernel(
    const float* __restrict__ feat,
    const unsigned int* __restrict__ fb,     // bf16 pairs, row = 32 uints
    const float* __restrict__ eps,
    const int* __restrict__ bcnt,            // padded counters = per-bucket totals
    const int* __restrict__ buckets,
    float* __restrict__ out)
{
    __shared__ int lcnt[NPB];
    __shared__ int sl[NPB * NCAP];               // 8 KB
    __shared__ int2 ovl[OVL_CAP];                // 1 KB
    __shared__ int ovl_n;
    const int tid  = threadIdx.x;
    const int k    = blockIdx.x;
    const int lane = tid & 63;
    const int w    = tid >> 6;

    if (tid < NPB) lcnt[tid] = 0;
    if (tid == 0) ovl_n = 0;
    __syncthreads();

    int m = bcnt[k * CNT_STRIDE];
    if (m > CAP_B) m = CAP_B;
    const int* __restrict__ bkt = buckets + k * CAP_B;
    for (int i = tid; i < m; i += 256) {         // coalesced, each entry once
        const int e  = bkt[i];
        const int ld = e >> 17;                  // 0..63
        const int t  = atomicAdd(&lcnt[ld], 1);  // LDS atomic
        if (t < NCAP) sl[ld * NCAP + t] = e & 0x1FFFF;
        else {                                   // deg > 32: exact in-block fallback
            const int o = atomicAdd(&ovl_n, 1);
            if (o < OVL_CAP) ovl[o] = make_int2(e & 0x1FFFF, ld);
        }
    }
    __syncthreads();

    const int r = lane >> 3;       // row-subgroup 0..7 (8 j-slots/trip)
    const int c = lane & 7;        // 16B chunk 0..7
    const float scale = 1.0f + eps[0];
    const int node_base = k * NPB;

    for (int nl = w * 16; nl < w * 16 + 16; nl += 4) {
        const int node0 = node_base + nl;
        int n0 = lcnt[nl];     if (n0 > NCAP) n0 = NCAP;
        int n1 = lcnt[nl + 1]; if (n1 > NCAP) n1 = NCAP;
        int n2 = lcnt[nl + 2]; if (n2 > NCAP) n2 = NCAP;
        int n3 = lcnt[nl + 3]; if (n3 > NCAP) n3 = NCAP;
        // lanes 0..31 hold the lists; 32..63 duplicate (shfl src always 0..31)
        const int ll = lane & (NCAP - 1);
        const int my0 = sl[(nl)     * NCAP + ll];
        const int my1 = sl[(nl + 1) * NCAP + ll];
        const int my2 = sl[(nl + 2) * NCAP + ll];
        const int my3 = sl[(nl + 3) * NCAP + ll];

        float a0[8], a1[8], a2[8], a3[8];
        #pragma unroll
        for (int x = 0; x < 8; ++x) { a0[x] = 0.f; a1[x] = 0.f; a2[x] = 0.f; a3[x] = 0.f; }

        int nmax = n0;
        if (n1 > nmax) nmax = n1;
        if (n2 > nmax) nmax = n2;
        if (n3 > nmax) nmax = n3;                // wave-uniform
        for (int j0 = 0; j0 < nmax; j0 += 8) {
            const int j  = j0 + r;
            const int j0c = (j < n0) ? j : 0;    // clamp: shfl src always valid
            const int j1c = (j < n1) ? j : 0;
            const int j2c = (j < n2) ? j : 0;
            const int j3c = (j < n3) ? j : 0;
            const int s0 = __shfl(my0, j0c);     // ALL 64 lanes active
            const int s1 = __shfl(my1, j1c);
            const int s2 = __shfl(my2, j2c);
            const int s3 = __shfl(my3, j3c);
            if (j < n0) {
                const uint4 q = *reinterpret_cast<const uint4*>(&fb[s0 * (D_FEAT / 2) + c * 4]);
                a0[0] += bf_lo(q.x); a0[1] += bf_hi(q.x);
                a0[2] += bf_lo(q.y); a0[3] += bf_hi(q.y);
                a0[4] += bf_lo(q.z); a0[5] += bf_hi(q.z);
                a0[6] += bf_lo(q.w); a0[7] += bf_hi(q.w);
            }
            if (j < n1) {
                const uint4 q = *reinterpret_cast<const uint4*>(&fb[s1 * (D_FEAT / 2) + c * 4]);
                a1[0] += bf_lo(q.x); a1[1] += bf_hi(q.x);
                a1[2] += bf_lo(q.y); a1[3] += bf_hi(q.y);
                a1[4] += bf_lo(q.z); a1[5] += bf_hi(q.z);
                a1[6] += bf_lo(q.w); a1[7] += bf_hi(q.w);
            }
            if (j < n2) {
                const uint4 q = *reinterpret_cast<const uint4*>(&fb[s2 * (D_FEAT / 2) + c * 4]);
                a2[0] += bf_lo(q.x); a2[1] += bf_hi(q.x);
                a2[2] += bf_lo(q.y); a2[3] += bf_hi(q.y);
                a2[4] += bf_lo(q.z); a2[5] += bf_hi(q.z);
                a2[6] += bf_lo(q.w); a2[7] += bf_hi(q.w);
            }
            if (j < n3) {
                const uint4 q = *reinterpret_cast<const uint4*>(&fb[s3 * (D_FEAT / 2) + c * 4]);
                a3[0] += bf_lo(q.x); a3[1] += bf_hi(q.x);
                a3[2] += bf_lo(q.y); a3[3] += bf_hi(q.y);
                a3[4] += bf_lo(q.z); a3[5] += bf_hi(q.z);
                a3[6] += bf_lo(q.w); a3[7] += bf_hi(q.w);
            }
        }
        // 3-stage butterfly across the 8 row-subgroups (xor 8, 16, 32)
        #pragma unroll
        for (int x = 0; x < 8; ++x) {
            a0[x] += __shfl_xor(a0[x], 8);  a1[x] += __shfl_xor(a1[x], 8);
            a2[x] += __shfl_xor(a2[x], 8);  a3[x] += __shfl_xor(a3[x], 8);
            a0[x] += __shfl_xor(a0[x], 16); a1[x] += __shfl_xor(a1[x], 16);
            a2[x] += __shfl_xor(a2[x], 16); a3[x] += __shfl_xor(a3[x], 16);
            a0[x] += __shfl_xor(a0[x], 32); a1[x] += __shfl_xor(a1[x], 32);
            a2[x] += __shfl_xor(a2[x], 32); a3[x] += __shfl_xor(a3[x], 32);
        }

        if (r == 0) {                            // lanes 0..7: 2 float4 per node
            #pragma unroll
            for (int q4 = 0; q4 < 4; ++q4) {
                const int node = node0 + q4;
                if (node < N_NODES) {
                    const float* acc = (q4 == 0) ? a0 : (q4 == 1) ? a1 : (q4 == 2) ? a2 : a3;
                    const float4 f0 = *reinterpret_cast<const float4*>(&feat[node * D_FEAT + c * 8]);
                    const float4 f1 = *reinterpret_cast<const float4*>(&feat[node * D_FEAT + c * 8 + 4]);
                    float4 o0, o1;
                    o0.x = scale * f0.x + acc[0]; o0.y = scale * f0.y + acc[1];
                    o0.z = scale * f0.z + acc[2]; o0.w = scale * f0.w + acc[3];
                    o1.x = scale * f1.x + acc[4]; o1.y = scale * f1.y + acc[5];
                    o1.z = scale * f1.z + acc[6]; o1.w = scale * f1.w + acc[7];
                    *reinterpret_cast<float4*>(&out[node * D_FEAT + c * 8]) = o0;
                    *reinterpret_cast<float4*>(&out[node * D_FEAT + c * 8 + 4]) = o1;
                }
            }
        }
    }

    // resolve per-node overflow (fp32-exact), after all stores in this block
    __syncthreads();
    int on = ovl_n; if (on > OVL_CAP) on = OVL_CAP;
    for (int i = w; i < on; i += 4) {            // one wave per overflow edge
        const int2 ov = ovl[i];
        atomicAdd(&out[(node_base + ov.y) * D_FEAT + lane],
                  feat[ov.x * D_FEAT + lane]);
    }
}

// ---- fallback path (ws too small): round-1 style ----
__global__ __launch_bounds__(256) void gin_init_kernel(
    const float* __restrict__ feat, const float* __restrict__ eps, float* __restrict__ out)
{
    const float scale = 1.0f + eps[0];
    int i = blockIdx.x * blockDim.x + threadIdx.x;
    if (i < (N_NODES * D_FEAT) / 4) {
        float4 v = reinterpret_cast<const float4*>(feat)[i];
        v.x *= scale; v.y *= scale; v.z *= scale; v.w *= scale;
        reinterpret_cast<float4*>(out)[i] = v;
    }
}
__global__ __launch_bounds__(256) void gin_scatter_kernel(
    const float* __restrict__ feat, const int* __restrict__ edge_src,
    const int* __restrict__ edge_dst, float* __restrict__ out)
{
    const int edge = blockIdx.x * 4 + (threadIdx.x >> 6);
    const int lane = threadIdx.x & 63;
    if (edge < N_EDGES)
        atomicAdd(&out[edge_dst[edge] * D_FEAT + lane], feat[edge_src[edge] * D_FEAT + lane]);
}

extern "C" void kernel_launch(void* const* d_in, const int* in_sizes, int n_in,
                              void* d_out, int out_size, void* d_ws, size_t ws_size,
                              hipStream_t stream)
{
    const float* feat     = (const float*)d_in[0];
    const float* eps      = (const float*)d_in[1];
    const int*   edge_src = (const int*)d_in[2];
    const int*   edge_dst = (const int*)d_in[3];
    float* out = (float*)d_out;

    // ws (ints): fb[N*D/2] | bcnt[KB*CNT_STRIDE] | buckets[KB*CAP_B]
    const size_t fb_ints   = (size_t)N_NODES * D_FEAT / 2;   // 3.2M
    const size_t bcnt_ints = (size_t)KB * CNT_STRIDE;        // 25008
    const size_t bkt_ints  = (size_t)KB * CAP_B;             // 1.6M
    const size_t need = sizeof(int) * (fb_ints + bcnt_ints + bkt_ints);  // ~19.3 MB
    if (ws_size >= need) {
        unsigned int* fb = (unsigned int*)d_ws;
        int* bcnt    = (int*)(fb + fb_ints);
        int* buckets = bcnt + bcnt_ints;

        // zero bucket counters (100 KB, graph-capturable)
        hipMemsetAsync(bcnt, 0, bcnt_ints * sizeof(int), stream);

        gin_cast_place_kernel<<<PB + CAST_BLOCKS, PTH, 0, stream>>>(
            feat, edge_src, edge_dst, fb, bcnt, buckets);
        gin_gather_kernel<<<KB, 256, 0, stream>>>(
            feat, fb, eps, bcnt, buckets, out);
    } else {
        const int total4 = (N_NODES * D_FEAT) / 4;
        gin_init_kernel<<<(total4 + 255) / 256, 256, 0, stream>>>(feat, eps, out);
        gin_scatter_kernel<<<(N_EDGES + 3) / 4, 256, 0, stream>>>(
            feat, edge_src, edge_dst, out);
    }
}